// Round 9
// baseline (51948.065 us; speedup 1.0000x reference)
//
#include <hip/hip_runtime.h>
#include <math.h>

namespace {
constexpr int BATCH = 128;
constexpr int SEQ   = 512;
constexpr int NL    = 32;
constexpr int BOSTAG = 1;
constexpr int EOSTAG = 2;
constexpr unsigned GRP = 128;   // blocks per barrier group (one per batch-half)
}

#define AL(p)    __hip_atomic_load((p),       __ATOMIC_RELAXED, __HIP_MEMORY_SCOPE_AGENT)
#define AS(p, v) __hip_atomic_store((p), (v), __ATOMIC_RELAXED, __HIP_MEMORY_SCOPE_AGENT)

__device__ unsigned int g_cnt[2];

__global__ void reset_cnt_kernel() {
  AS(&g_cnt[0], 0u);
  AS(&g_cnt[1], 0u);
}

// coherent (L1/L2-bypass) float4 load, element-wise relaxed agent atomics
__device__ __forceinline__ float4 aload4(const float* p) {
  float4 v;
  v.x = AL(p + 0); v.y = AL(p + 1); v.z = AL(p + 2); v.w = AL(p + 3);
  return v;
}

// Group barrier (128 blocks = one batch-half, both dirs). NO cache fence:
// cross-block data moves via agent-scope write-through stores (drained by the
// vmcnt(0) the compiler emits before s_barrier, i.e. before the counter add)
// and agent-scope bypass loads on the reader side. Read-only data stays cached.
__device__ __forceinline__ void gbar(int ci, unsigned target) {
  __syncthreads();
  if (threadIdx.x == 0) {
    __hip_atomic_fetch_add(&g_cnt[ci], 1u, __ATOMIC_RELAXED, __HIP_MEMORY_SCOPE_AGENT);
    while (AL(&g_cnt[ci]) < target)
      __builtin_amdgcn_s_sleep(2);
  }
  __syncthreads();
}

// hbuf layout: [2 parity][2 dir][128 b][512 u]  (65536 floats per (par,dir))
__global__ __launch_bounds__(512, 1)
void bilstm_coop(const int* __restrict__ x,
                 const float* __restrict__ emb,
                 const float* __restrict__ Wih_f, const float* __restrict__ Whh_f, const float* __restrict__ bf,
                 const float* __restrict__ Wih_b, const float* __restrict__ Whh_b, const float* __restrict__ bbias,
                 const float* __restrict__ Wout, const float* __restrict__ bout,
                 float* __restrict__ hbuf, float* __restrict__ em)
{
  __shared__ float4 WT4[8192];       // [k(1024)][slot(8)] gates i,f,g,o in .xyzw; slot = uu ^ ((k>>2)&7). 128 KB
  __shared__ float  em_red[2][512];  // parity-double-buffered emission partials [kc(16)*32 + l(32)]
  float* WTf = (float*)WT4;

  const int tid = threadIdx.x, bi = blockIdx.x;
  const int dir = bi >> 7, bidx = bi & 127;
  const int ug  = bidx >> 1, bh = bidx & 1;    // ug: 8-unit slice, bh: batch half
  const int u0  = ug * 8, b_base = bh * 64;
  const int bb  = b_base + ug;                 // emission batch owned by this block

  const float* Wih = dir ? Wih_b : Wih_f;
  const float* Whh = dir ? Whh_b : Whh_f;
  const float* bv  = dir ? bbias : bf;

  // ---- one-time: W slice -> LDS. WT4[k*8+slot] = gates of unit uu=slot^((k>>2)&7)
  for (int idx = tid; idx < 32768; idx += 512) {
    const int k = idx >> 5, r = idx & 31;
    const int gate = r & 3, uu = r >> 2;
    const int grow = gate * 512 + u0 + uu;
    const float v = (k < 512) ? Wih[(size_t)grow * 512 + k]
                              : Whh[(size_t)grow * 512 + (k - 512)];
    WTf[k * 32 + ((uu ^ ((k >> 2) & 7)) << 2) + gate] = v;
  }

  // compute roles: thread = (ks: k-split 8, ug2: unit-pair 4, bq: batch-quad 16)
  const int ks   = tid & 7;
  const int ug2  = (tid >> 3) & 3;
  const int bq   = ((tid >> 5) & 1) + 2 * (tid >> 6);   // 0..15
  const int bB   = b_base + 4 * bq;                      // first of 4 owned batches
  const int wb0 = 32 * ks + ((2 * ug2 + 0) ^ ks);
  const int wb1 = 32 * ks + ((2 * ug2 + 1) ^ ks);
  const int u_own = u0 + 2 * ug2 + (ks & 1);
  const int b_own = bB + (ks >> 1);
  // emission roles: l_ = label, kc = k-chunk of 32
  const int l_ = tid >> 4, kc = tid & 15;

  float bias_g[4];
  #pragma unroll
  for (int g = 0; g < 4; ++g) bias_g[g] = bv[g * 512 + u_own];
  float cstate = 0.f;

  // init parity-1 h: this block zeroes its own bb row (group-local dependency)
  AS(&hbuf[131072 + dir * 65536 + (size_t)bb * 512 + tid], 0.f);
  unsigned epoch = 1;
  gbar(bh, GRP * epoch); ++epoch;

  for (int s = 0; s < SEQ; ++s) {
    const int t = dir ? (SEQ - 1 - s) : s;

    // ---- pre-barrier: x + emb ring slots 0..2 (plain cached; complete during spin)
    const float* e0 = emb + (size_t)x[(bB + 0) * SEQ + t] * 512 + 4 * ks;
    const float* e1 = emb + (size_t)x[(bB + 1) * SEQ + t] * 512 + 4 * ks;
    const float* e2 = emb + (size_t)x[(bB + 2) * SEQ + t] * 512 + 4 * ks;
    const float* e3 = emb + (size_t)x[(bB + 3) * SEQ + t] * 512 + 4 * ks;
    float4 ring[4][4];
    #pragma unroll
    for (int sl = 0; sl < 3; ++sl) {
      ring[sl][0] = *(const float4*)(e0 + sl * 32);
      ring[sl][1] = *(const float4*)(e1 + sl * 32);
      ring[sl][2] = *(const float4*)(e2 + sl * 32);
      ring[sl][3] = *(const float4*)(e3 + sl * 32);
    }

    gbar(bh, GRP * epoch); ++epoch;

    const float* hprev = hbuf + (size_t)((s + 1) & 1) * 131072 + dir * 65536;
    float*       hout  = hbuf + (size_t)((s    ) & 1) * 131072 + dir * 65536;

    // ---- issue emission h loads for h_{s-1} (bypass; consumed mid-step) ----
    float4 hq[8];
    if (s > 0) {
      const float* hb2 = hprev + (size_t)bb * 512 + kc * 32;
      #pragma unroll
      for (int q = 0; q < 8; ++q) hq[q] = aload4(hb2 + q * 4);
    }

    // ---- finalize emission of h_{s-2} from last step's em_red (no sync needed:
    //      reads buffer (s-1)&1, this step writes s&1; gbar ordered the writes)
    if (s >= 2 && tid < 32) {
      float p = 0.f;
      #pragma unroll
      for (int ksi = 0; ksi < 16; ++ksi) p += em_red[(s - 1) & 1][ksi * 32 + tid];
      const int te = dir ? (SEQ - (s - 1)) : (s - 2);
      const bool first = dir ? (te >= 256) : (te < 256);
      float* dst = em + ((size_t)bb * SEQ + te) * NL + tid;
      if (first) AS(dst, p + bout[tid]);
      else       { const float old = AL(dst); AS(dst, old + p); }
    }

    // ---- gate GEMM: acc[unit n][batch r][gate], depth-3 ring prefetch ----
    float acc0[4][4], acc1[4][4];
    #pragma unroll
    for (int r = 0; r < 4; ++r)
      #pragma unroll
      for (int g = 0; g < 4; ++g) { acc0[r][g] = 0.f; acc1[r][g] = 0.f; }

    const float* h0 = hprev + (size_t)(bB + 0) * 512 + 4 * ks;
    const float* h1 = hprev + (size_t)(bB + 1) * 512 + 4 * ks;
    const float* h2 = hprev + (size_t)(bB + 2) * 512 + 4 * ks;
    const float* h3 = hprev + (size_t)(bB + 3) * 512 + 4 * ks;

    // emb half: k = 4ks + 32i + j ; iters 13..15 pre-warm the h ring (bypass loads)
    #pragma unroll 4
    for (int i = 0; i < 16; ++i) {
      const int cs = i & 3, ns = (i + 3) & 3;
      if (i < 13) {
        ring[ns][0] = *(const float4*)(e0 + (i + 3) * 32);
        ring[ns][1] = *(const float4*)(e1 + (i + 3) * 32);
        ring[ns][2] = *(const float4*)(e2 + (i + 3) * 32);
        ring[ns][3] = *(const float4*)(e3 + (i + 3) * 32);
      } else {
        ring[ns][0] = aload4(h0 + (i - 13) * 32);
        ring[ns][1] = aload4(h1 + (i - 13) * 32);
        ring[ns][2] = aload4(h2 + (i - 13) * 32);
        ring[ns][3] = aload4(h3 + (i - 13) * 32);
      }
      #pragma unroll
      for (int j = 0; j < 4; ++j) {
        const float4 w0 = WT4[wb0 + 256 * i + 8 * j];
        const float4 w1 = WT4[wb1 + 256 * i + 8 * j];
        #pragma unroll
        for (int r = 0; r < 4; ++r) {
          const float a = (j == 0) ? ring[cs][r].x : (j == 1) ? ring[cs][r].y
                        : (j == 2) ? ring[cs][r].z : ring[cs][r].w;
          acc0[r][0] = fmaf(w0.x, a, acc0[r][0]);
          acc0[r][1] = fmaf(w0.y, a, acc0[r][1]);
          acc0[r][2] = fmaf(w0.z, a, acc0[r][2]);
          acc0[r][3] = fmaf(w0.w, a, acc0[r][3]);
          acc1[r][0] = fmaf(w1.x, a, acc1[r][0]);
          acc1[r][1] = fmaf(w1.y, a, acc1[r][1]);
          acc1[r][2] = fmaf(w1.z, a, acc1[r][2]);
          acc1[r][3] = fmaf(w1.w, a, acc1[r][3]);
        }
      }
    }

    // ---- emission partial for h_{s-1} (hq long since landed); no sync ----
    if (s > 0) {
      const float* wr_ = Wout + (size_t)l_ * 1024 + dir * 512 + kc * 32;
      float emP = 0.f;
      #pragma unroll
      for (int q = 0; q < 8; ++q) {
        const float4 wv = *(const float4*)&wr_[q * 4];
        emP = fmaf(hq[q].x, wv.x, emP);
        emP = fmaf(hq[q].y, wv.y, emP);
        emP = fmaf(hq[q].z, wv.z, emP);
        emP = fmaf(hq[q].w, wv.w, emP);
      }
      em_red[s & 1][kc * 32 + l_] = emP;
    }

    // h half: k = 512 + 4ks + 32i + j
    #pragma unroll 4
    for (int i = 0; i < 16; ++i) {
      const int cs = i & 3, ns = (i + 3) & 3;
      if (i < 13) {
        ring[ns][0] = aload4(h0 + (i + 3) * 32);
        ring[ns][1] = aload4(h1 + (i + 3) * 32);
        ring[ns][2] = aload4(h2 + (i + 3) * 32);
        ring[ns][3] = aload4(h3 + (i + 3) * 32);
      }
      #pragma unroll
      for (int j = 0; j < 4; ++j) {
        const float4 w0 = WT4[4096 + wb0 + 256 * i + 8 * j];
        const float4 w1 = WT4[4096 + wb1 + 256 * i + 8 * j];
        #pragma unroll
        for (int r = 0; r < 4; ++r) {
          const float a = (j == 0) ? ring[cs][r].x : (j == 1) ? ring[cs][r].y
                        : (j == 2) ? ring[cs][r].z : ring[cs][r].w;
          acc0[r][0] = fmaf(w0.x, a, acc0[r][0]);
          acc0[r][1] = fmaf(w0.y, a, acc0[r][1]);
          acc0[r][2] = fmaf(w0.z, a, acc0[r][2]);
          acc0[r][3] = fmaf(w0.w, a, acc0[r][3]);
          acc1[r][0] = fmaf(w1.x, a, acc1[r][0]);
          acc1[r][1] = fmaf(w1.y, a, acc1[r][1]);
          acc1[r][2] = fmaf(w1.z, a, acc1[r][2]);
          acc1[r][3] = fmaf(w1.w, a, acc1[r][3]);
        }
      }
    }

    // ---- butterfly over the 8 ks lanes (xor 1,2,4) ----
    #pragma unroll
    for (int m = 1; m < 8; m <<= 1)
      #pragma unroll
      for (int r = 0; r < 4; ++r)
        #pragma unroll
        for (int g = 0; g < 4; ++g) {
          acc0[r][g] += __shfl_xor(acc0[r][g], m, 64);
          acc1[r][g] += __shfl_xor(acc1[r][g], m, 64);
        }

    // lane ks owns (unit n'=ks&1, batch r'=ks>>1): static ternary select
    {
      float g4[4];
      #pragma unroll
      for (int g = 0; g < 4; ++g) {
        float v = acc0[0][g];
        v = (ks == 1) ? acc1[0][g] : v;
        v = (ks == 2) ? acc0[1][g] : v;
        v = (ks == 3) ? acc1[1][g] : v;
        v = (ks == 4) ? acc0[2][g] : v;
        v = (ks == 5) ? acc1[2][g] : v;
        v = (ks == 6) ? acc0[3][g] : v;
        v = (ks == 7) ? acc1[3][g] : v;
        g4[g] = v;
      }
      const float gi = g4[0] + bias_g[0];
      const float gf = g4[1] + bias_g[1];
      const float gg = g4[2] + bias_g[2];
      const float go = g4[3] + bias_g[3];
      const float si = 1.f / (1.f + expf(-gi));
      const float sf = 1.f / (1.f + expf(-gf));
      const float so = 1.f / (1.f + expf(-go));
      cstate = sf * cstate + si * tanhf(gg);
      AS(&hout[(size_t)b_own * 512 + u_own], so * tanhf(cstate));
    }
  }
  gbar(bh, GRP * epoch); ++epoch;

  // ---- tail: finalize h_510 (partials in em_red[1], written at s=511) ----
  if (tid < 32) {
    float p = 0.f;
    #pragma unroll
    for (int ksi = 0; ksi < 16; ++ksi) p += em_red[1][ksi * 32 + tid];
    const int te = dir ? 1 : 510;           // both dirs: accumulate (not first)
    float* dst = em + ((size_t)bb * SEQ + te) * NL + tid;
    const float old = AL(dst); AS(dst, old + p);
  }
  // ---- tail: emission of h_511 (parity-1 buffer) ----
  {
    const float* hb2 = hbuf + 131072 + dir * 65536 + (size_t)bb * 512 + kc * 32;
    const float* wr_ = Wout + (size_t)l_ * 1024 + dir * 512 + kc * 32;
    float emP = 0.f;
    #pragma unroll
    for (int q = 0; q < 8; ++q) {
      const float4 hv = aload4(hb2 + q * 4);
      const float4 wv = *(const float4*)&wr_[q * 4];
      emP = fmaf(hv.x, wv.x, emP);
      emP = fmaf(hv.y, wv.y, emP);
      emP = fmaf(hv.z, wv.z, emP);
      emP = fmaf(hv.w, wv.w, emP);
    }
    em_red[0][kc * 32 + l_] = emP;
    __syncthreads();
    if (tid < 32) {
      float p = 0.f;
      #pragma unroll
      for (int ksi = 0; ksi < 16; ++ksi) p += em_red[0][ksi * 32 + tid];
      const int te = dir ? 0 : 511;         // both dirs: accumulate
      float* dst = em + ((size_t)bb * SEQ + te) * NL + tid;
      const float old = AL(dst); AS(dst, old + p);
    }
  }
}

__global__ __launch_bounds__(64)
void viterbi_kernel(const float* __restrict__ em, const int* __restrict__ mask,
                    const float* __restrict__ trans, float* __restrict__ out)
{
  __shared__ float tr[32][33];
  __shared__ float alpha[32];
  __shared__ float fin[32];
  __shared__ unsigned char bp[SEQ][32];
  __shared__ float path[SEQ];

  const int b = blockIdx.x, tid = threadIdx.x;
  for (int i = tid; i < 1024; i += 64) tr[i >> 5][i & 31] = trans[i];
  __syncthreads();

  const float* emB = em + (size_t)b * SEQ * NL;
  if (tid < 32) alpha[tid] = tr[BOSTAG][tid] + emB[tid];
  __syncthreads();

  for (int t = 1; t < SEQ; ++t) {
    float best = -INFINITY, e = 0.f;
    int arg = 0;
    if (tid < 32) {
      e = emB[t * NL + tid];
      #pragma unroll 4
      for (int p = 0; p < 32; ++p) {
        const float sc = (alpha[p] + tr[p][tid]) + e;  // np broadcast order
        if (sc > best) { best = sc; arg = p; }          // first-occurrence argmax
      }
    }
    __syncthreads();
    if (tid < 32) {
      const float m = (float)mask[b * SEQ + t];
      alpha[tid] = m * best + (1.f - m) * alpha[tid];
      bp[t][tid] = (unsigned char)arg;
    }
    __syncthreads();
  }

  if (tid < 32) fin[tid] = alpha[tid] + tr[tid][EOSTAG];
  __syncthreads();

  if (tid == 0) {
    float best = fin[0]; int tag = 0;
    for (int n = 1; n < 32; ++n) if (fin[n] > best) { best = fin[n]; tag = n; }
    out[b] = best;
    path[SEQ - 1] = (float)tag;
    for (int k = SEQ - 2; k >= 0; --k) {
      const int prev = bp[k + 1][tag];
      if (mask[b * SEQ + k + 1] > 0) tag = prev;
      path[k] = (float)tag;
    }
  }
  __syncthreads();
  for (int idx = tid; idx < SEQ; idx += 64)
    out[BATCH + (size_t)b * SEQ + idx] = path[idx];
}

extern "C" void kernel_launch(void* const* d_in, const int* in_sizes, int n_in,
                              void* d_out, int out_size, void* d_ws, size_t ws_size,
                              hipStream_t stream) {
  (void)in_sizes; (void)n_in; (void)out_size; (void)ws_size;
  const int*   x     = (const int*)d_in[0];
  const int*   mask  = (const int*)d_in[1];
  const float* emb   = (const float*)d_in[2];
  const float* Wih_f = (const float*)d_in[3];
  const float* Whh_f = (const float*)d_in[4];
  const float* bf    = (const float*)d_in[5];
  const float* Wih_b = (const float*)d_in[6];
  const float* Whh_b = (const float*)d_in[7];
  const float* bb    = (const float*)d_in[8];
  const float* Wout  = (const float*)d_in[9];
  const float* bout  = (const float*)d_in[10];
  const float* trans = (const float*)d_in[11];
  float* out  = (float*)d_out;
  float* hbuf = (float*)d_ws;                   // 262144 floats (1 MB)
  float* em   = hbuf + 262144;                  // 2097152 floats (8 MB)

  reset_cnt_kernel<<<dim3(1), dim3(1), 0, stream>>>();

  void* args[] = { (void*)&x, (void*)&emb,
                   (void*)&Wih_f, (void*)&Whh_f, (void*)&bf,
                   (void*)&Wih_b, (void*)&Whh_b, (void*)&bb,
                   (void*)&Wout, (void*)&bout,
                   (void*)&hbuf, (void*)&em };
  hipLaunchCooperativeKernel((void*)bilstm_coop, dim3(256), dim3(512), args, 0, stream);
  viterbi_kernel<<<dim3(128), dim3(64), 0, stream>>>(em, mask, trans, out);
}